// Round 1
// 136.189 us; speedup vs baseline: 1.0002x; 1.0002x over previous
//
#include <hip/hip_runtime.h>
#include <math.h>

// Problem constants (reference: B=64, N=512, K=32, D=64)
#define BB 64
#define NN 512
#define KK 32
#define DD 64
#define BN (BB*NN)          // 32768
#define EPSC 1e-5f
#define NEG_SLOPE 0.2f
#define NEG_INF_A (-1e9f)

typedef unsigned long long ull;

// Lessons carried: (R1) f32 inputs, not bf16. (R5) per-lane row loads from
// global are uncoalesced -> stage via LDS. (R6) lane*16+q LDS reads are
// 16-way bank-conflicted -> XOR swizzle slot = q ^ (row&15). (R7) never put
// __shfl under divergent control flow. (R9) don't fuse away tiling reuse.
// (R10+) producer/consumer XCD alignment: lin role writes xl for batch b on
// XCD b%8, where k3's readers of batch b also run -> gathers hit local L2.
// (R11, this round) block-role fusion: graph-build (cos+rank) is independent
// of the lin GEMM once ei/ej are folded into k2's existing butterfly, so both
// run in ONE dispatch; keys never leave LDS.

// ---------------------------------------------------------------------------
// K1: fused prep, grid = 1536 blocks x 256 threads.
//   blocks 0..1023   (role A): xl = x @ W^T; si/sj with emb-term folded into
//                              the same per-row butterfly (no ei/ej dep).
//   blocks 1024..1535 (role B): one block per node row i: cos row (mat-vec
//                              against emb), order-preserving keys in LDS,
//                              exact lax.top_k rank selection. Block i==0
//                              also folds the BN constants (epi).
// ---------------------------------------------------------------------------
__global__ void k1_prep(const float* __restrict__ data,
                        const float* __restrict__ linW,
                        const float* __restrict__ emb,
                        const float* __restrict__ att_i,
                        const float* __restrict__ att_j,
                        const float* __restrict__ attemi,
                        const float* __restrict__ attemj,
                        const float* __restrict__ gnn_bias,
                        const float* __restrict__ g1, const float* __restrict__ b1,
                        const float* __restrict__ m1, const float* __restrict__ v1,
                        const float* __restrict__ go, const float* __restrict__ bo,
                        const float* __restrict__ mo, const float* __restrict__ vo,
                        float* __restrict__ xl, float* __restrict__ si,
                        float* __restrict__ sj, int* __restrict__ topk,
                        float* __restrict__ epi) {
    __shared__ __align__(16) char smem[24576];   // role A: Ws(16K)+xs(8K); role B: ks(4K)+Ai(256B)
    const int t = threadIdx.x;
    const int bid = blockIdx.x;

    if (bid < 1024) {
        // ---------------- role A: lin + si/sj ----------------
        float4* Ws = (float4*)smem;              // 16 KiB, XOR-swizzled full W
        float4* xs = (float4*)(smem + 16384);    // 8 KiB, 32 input rows
        const int lane = t & 63;
        const int wave = t >> 6;
        const float4* W4 = (const float4*)linW;

        // XCD-aligned mapping (identical to previous k2): batch b on XCD b%8.
        const int xcd = bid & 7;
        const int j   = bid >> 3;                // 0..127
        const int batch = xcd + 8 * (j >> 4);
        const int sub   = j & 15;
        const int row0  = batch * NN + sub * 32; // 32 rows, all in batch `batch`

        #pragma unroll
        for (int p = 0; p < 4; ++p) {            // swizzled full-W stage (coalesced)
            const int idx = t + 256*p;
            const int r = idx >> 4, q = idx & 15;
            Ws[(r<<4) | (q ^ (r & 15))] = W4[idx];
        }
        xs[t]       = ((const float4*)data)[row0*16 + t];
        xs[t + 256] = ((const float4*)data)[row0*16 + t + 256];
        __syncthreads();

        float4 Wr[16];                           // W[lane][0..63], swizzled read
        #pragma unroll
        for (int q = 0; q < 16; ++q) Wr[q] = Ws[(lane<<4) | (q ^ (lane & 15))];

        const int r0 = wave * 8;                 // 8 rows per wave
        float acc[8] = {0.f, 0.f, 0.f, 0.f, 0.f, 0.f, 0.f, 0.f};
        #pragma unroll
        for (int q = 0; q < 16; ++q) {
            const float4 w = Wr[q];
            #pragma unroll
            for (int r = 0; r < 8; ++r) {
                const float4 x = xs[(r0+r)*16 + q];  // wave-uniform broadcasts
                acc[r] += x.x*w.x + x.y*w.y + x.z*w.z + x.w*w.w;
            }
        }

        const int vbase = row0 + r0;
        #pragma unroll
        for (int r = 0; r < 8; ++r) xl[(vbase+r)*DD + lane] = acc[r];

        // si/sj with the emb attention term folded in BEFORE the reduce:
        // si[v] = sum_d( xl[v][d]*att_i[d] + emb[node][d]*att_em_i[d] )
        const float ai  = att_i[lane];
        const float aj  = att_j[lane];
        const float aei = attemi[lane];
        const float aej = attemj[lane];
        const int node0 = sub*32 + r0;           // node id of row vbase
        #pragma unroll
        for (int r = 0; r < 8; ++r) {
            const float em = emb[(node0 + r)*DD + lane];   // coalesced 256B
            float pi = acc[r]*ai + em*aei;
            float pj = acc[r]*aj + em*aej;
            #pragma unroll
            for (int m = 32; m > 0; m >>= 1) {
                pi += __shfl_xor(pi, m);
                pj += __shfl_xor(pj, m);
            }
            if (lane == 0) {
                const int v = vbase + r;
                si[v] = pi;
                sj[v] = pj;
            }
        }
    } else {
        // ---------------- role B: cos row + rank ----------------
        const int i = bid - 1024;                // node row 0..511
        ull*    ks = (ull*)smem;                 // 512 keys, 4 KiB
        float4* Ai = (float4*)(smem + 4096);     // row i, 256 B

        if (t < 16) Ai[t] = ((const float4*)emb)[i*16 + t];
        __syncthreads();

        // row-i fragment + inverse norm (LDS broadcast reads, conflict-free)
        float4 Af[16];
        float ssA = 0.f;
        #pragma unroll
        for (int q = 0; q < 16; ++q) {
            Af[q] = Ai[q];
            ssA += Af[q].x*Af[q].x + Af[q].y*Af[q].y + Af[q].z*Af[q].z + Af[q].w*Af[q].w;
        }
        const float rsA = rsqrtf(ssA);
        const float4* e4 = (const float4*)emb;

        // thread t owns cols t and t+256: dot + col norm in one pass.
        // Per-wave footprint 16KB of emb, L1/L2-resident (emb is hot).
        #pragma unroll
        for (int half = 0; half < 2; ++half) {
            const int jc = t + 256*half;
            float acc = 0.f, ss = 0.f;
            #pragma unroll
            for (int q = 0; q < 16; ++q) {
                const float4 w = e4[jc*16 + q];
                acc += Af[q].x*w.x + Af[q].y*w.y + Af[q].z*w.z + Af[q].w*w.w;
                ss  += w.x*w.x + w.y*w.y + w.z*w.z + w.w*w.w;
            }
            const float c = acc * rsA * rsqrtf(ss);
            unsigned int u = __float_as_uint(c);
            u = (u & 0x80000000u) ? ~u : (u | 0x80000000u);   // order-preserving bits
            ks[jc] = ((ull)u << 16) | (ull)(NN - 1 - jc);     // tiebreak = lower col first
        }
        __syncthreads();

        // rank = #{key > mine}; keys unique -> exact lax.top_k order.
        // Two columns share each ds_read (2 cmps per 8B read).
        const ull k1 = ks[t];
        const ull k2 = ks[t + 256];
        int r1 = 0, r2 = 0;
        #pragma unroll 16
        for (int kk = 0; kk < NN; ++kk) {
            const ull kv = ks[kk];
            r1 += (kv > k1) ? 1 : 0;
            r2 += (kv > k2) ? 1 : 0;
        }
        if (r1 < KK) topk[i*KK + r1] = t;
        if (r2 < KK) topk[i*KK + r2] = t + 256;

        // BN-constant fold (once, any block — use row 0)
        if (i == 0 && t < DD) {
            const int d = t;
            const float s1 = g1[d] / sqrtf(v1[d] + EPSC);
            const float B1 = (gnn_bias[d] - m1[d]) * s1 + b1[d];
            const float so = go[d] / sqrtf(vo[d] + EPSC);
            const float Bo = bo[d] - mo[d] * so;
            epi[d] = s1; epi[DD + d] = B1; epi[2*DD + d] = so; epi[3*DD + d] = Bo;
        }
    }
}

// ---------------------------------------------------------------------------
// K3: one wave per target. Softmax (lane=edge) then BATCHED float4 gather
// (9 loads in flight -> MLP), butterfly reduce, folded-BN epilogue.
// XCD swizzle: batch b on XCD b%8 (matches role A's producer placement).
// ---------------------------------------------------------------------------
__global__ void k3_agg(const float* __restrict__ xl, const float* __restrict__ si,
                       const float* __restrict__ sj, const int* __restrict__ topk,
                       const float* __restrict__ emb,
                       const float* __restrict__ epi,
                       const float* __restrict__ outW, const float* __restrict__ outb,
                       float* __restrict__ out) {
    const int t = threadIdx.x;
    const int lane = t & 63;
    const int wave = t >> 6;
    const int bid = blockIdx.x;              // 8192 blocks
    const int xcd = bid & 7;
    const int ixc = bid >> 3;                // 0..1023
    const int b   = xcd + 8 * (ixc >> 7);    // batch 0..63, b%8 == xcd
    const int i   = ((ixc & 127) << 2) + wave;
    const int tgt = b * NN + i;

    // --- phase 1: lane k (0..32) = edge ---
    const bool isedge = (lane <= KK);
    int tk = i;
    bool valid = true;
    if (lane < KK) { tk = topk[i*KK + lane]; valid = (tk != i); }
    const int srcg = b * NN + tk;

    float a;
    if (isedge) {
        a = si[tgt] + sj[srcg];
        a = (a >= 0.f) ? a : NEG_SLOPE * a;   // leaky_relu
        if (!valid) a = NEG_INF_A;            // mask AFTER leaky (matches ref)
    } else {
        a = -3.0e38f;
    }

    float amax = a;
    #pragma unroll
    for (int m = 32; m > 0; m >>= 1) amax = fmaxf(amax, __shfl_xor(amax, m));

    float ex = (isedge && valid) ? __expf(a - amax) : 0.f;
    float denom = ex;
    #pragma unroll
    for (int m = 32; m > 0; m >>= 1) denom += __shfl_xor(denom, m);
    const float alpha = ex * __builtin_amdgcn_rcpf(denom);

    // --- phase 2: batched float4 gather, lane = (e4, c4) ---
    const int c4 = lane & 15;
    const int e4 = lane >> 4;
    const float4* xl4 = (const float4*)xl;

    float al[9];
    int   off[9];
    #pragma unroll
    for (int m = 0; m < 8; ++m) {
        const int kk = 4*m + e4;
        al[m]  = __shfl(alpha, kk);          // all lanes active
        off[m] = __shfl(srcg, kk)*16 + c4;
    }
    const float alpha32 = __shfl(alpha, KK); // full wave active
    const int   srcg32  = __shfl(srcg, KK);
    al[8]  = (e4 == 0) ? alpha32 : 0.f;
    off[8] = srcg32*16 + c4;

    float4 xv[9];
    #pragma unroll
    for (int m = 0; m < 9; ++m) xv[m] = xl4[off[m]];  // 9 loads in flight

    float4 acc = make_float4(0.f, 0.f, 0.f, 0.f);
    #pragma unroll
    for (int m = 0; m < 9; ++m) {
        acc.x += al[m]*xv[m].x; acc.y += al[m]*xv[m].y;
        acc.z += al[m]*xv[m].z; acc.w += al[m]*xv[m].w;
    }

    #pragma unroll
    for (int m = 16; m <= 32; m <<= 1) {
        acc.x += __shfl_xor(acc.x, m);
        acc.y += __shfl_xor(acc.y, m);
        acc.z += __shfl_xor(acc.z, m);
        acc.w += __shfl_xor(acc.w, m);
    }

    const float4* epi4 = (const float4*)epi;
    const float4 s1 = epi4[c4];
    const float4 B1 = epi4[16 + c4];
    const float4 so = epi4[32 + c4];
    const float4 Bo = epi4[48 + c4];
    const float4 em = ((const float4*)emb)[i*16 + c4];
    const float4 w4 = ((const float4*)outW)[c4];
    float4 h;
    h.x = fmaxf(acc.x*s1.x + B1.x, 0.f) * em.x;
    h.y = fmaxf(acc.y*s1.y + B1.y, 0.f) * em.y;
    h.z = fmaxf(acc.z*s1.z + B1.z, 0.f) * em.z;
    h.w = fmaxf(acc.w*s1.w + B1.w, 0.f) * em.w;
    h.x = fmaxf(h.x*so.x + Bo.x, 0.f);
    h.y = fmaxf(h.y*so.y + Bo.y, 0.f);
    h.z = fmaxf(h.z*so.z + Bo.z, 0.f);
    h.w = fmaxf(h.w*so.w + Bo.w, 0.f);
    float p = h.x*w4.x + h.y*w4.y + h.z*w4.z + h.w*w4.w;
    p += __shfl_xor(p, 1);
    p += __shfl_xor(p, 2);
    p += __shfl_xor(p, 4);
    p += __shfl_xor(p, 8);
    if (lane == 0) out[tgt] = p + outb[0];
}

// ---------------------------------------------------------------------------
extern "C" void kernel_launch(void* const* d_in, const int* in_sizes, int n_in,
                              void* d_out, int out_size, void* d_ws, size_t ws_size,
                              hipStream_t stream) {
    (void)in_sizes; (void)n_in; (void)out_size; (void)ws_size;
    const float* data   = (const float*)d_in[0];
    // d_in[1] = org_edge_index (int32) — unused by the reference forward
    const float* emb    = (const float*)d_in[2];
    const float* linW   = (const float*)d_in[3];
    const float* att_i  = (const float*)d_in[4];
    const float* att_j  = (const float*)d_in[5];
    const float* attemi = (const float*)d_in[6];
    const float* attemj = (const float*)d_in[7];
    const float* gbias  = (const float*)d_in[8];
    const float* g1     = (const float*)d_in[9];
    const float* b1     = (const float*)d_in[10];
    const float* m1     = (const float*)d_in[11];
    const float* v1     = (const float*)d_in[12];
    const float* go     = (const float*)d_in[13];
    const float* bo     = (const float*)d_in[14];
    const float* mo     = (const float*)d_in[15];
    const float* vo     = (const float*)d_in[16];
    const float* outW   = (const float*)d_in[17];
    const float* outb   = (const float*)d_in[18];
    float* out = (float*)d_out;

    // Workspace layout (bytes):
    //   epi @8K (1K)  topk @16K (64K)
    //   si @80K (128K)  sj @208K (128K)  xl @336K (8M)
    char* ws = (char*)d_ws;
    float* epi  = (float*)(ws + 8192);
    int*   topk = (int*)  (ws + 16384);
    float* si   = (float*)(ws + 81920);
    float* sj   = (float*)(ws + 212992);
    float* xl   = (float*)(ws + 344064);

    k1_prep<<<1536, 256, 0, stream>>>(data, linW, emb, att_i, att_j,
                                      attemi, attemj, gbias,
                                      g1, b1, m1, v1, go, bo, mo, vo,
                                      xl, si, sj, topk, epi);
    k3_agg<<<BN/4, 256, 0, stream>>>(xl, si, sj, topk, emb, epi,
                                     outW, outb, out);
}